// Round 7
// baseline (827.681 us; speedup 1.0000x reference)
//
#include <hip/hip_runtime.h>

typedef _Float16 f16;
typedef _Float16 f16x8 __attribute__((ext_vector_type(8)));
typedef float f32x4 __attribute__((ext_vector_type(4)));

#define Bn 8
#define Him 512
#define Wim 256
#define NPK 18
#define RAD 5
#define PTHRESH 0.1f
#define BN_EPS 1e-5f

// d_out layout (floats)
#define SZ_HM   (Bn*2*Him*Wim)
#define OFF_UP  (SZ_HM)
#define OFF_LO  (OFF_UP + Bn*NPK*2)
#define OFF_MID (OFF_LO + Bn*NPK*2)
#define OFF_VEC (OFF_MID + Bn*NPK*2)

// ---- fast-path ws layout: xh padded NHWC f16, then swizzled weights, then alpha/beta
#define PH (Him + 2)                 // 514
#define PW (Wim + 2)                 // 258
#define XH_ELT ((size_t)Bn * PH * PW * 32)
#define XH_BYTES (XH_ELT * 2)        // 67,897,344
#define WBYTES 73728
#define WS_NEED (XH_BYTES + WBYTES + 1024)

// ---- fallback (round-2) ws layout
#define WS_WBYTES 73728
#define XCOLS 258
#define XSTR  40

// =====================================================================
// FAST PATH
// =====================================================================

// ---------------- xform: x [8][32][512][256] f32 -> xh [8][514][258][32] f16 (zero halo)
__global__ __launch_bounds__(256) void xform_kernel(
    const float* __restrict__ x, f16* __restrict__ xh)
{
    int e = blockIdx.x * 256 + threadIdx.x;          // 4,243,584 total
    if (e >= Bn * PH * PW * 4) return;
    int cb  = e & 3;                                  // 8-ch chunk
    int pxl = e >> 2;                                 // padded pixel linear
    int b   = pxl / (PH * PW);
    int rem = pxl - b * (PH * PW);
    int yy  = rem / PW;
    int xx  = rem - yy * PW;
    int yv = yy - 1, xv = xx - 1;
    f16x8 hv;
    if ((unsigned)yv < (unsigned)Him && (unsigned)xv < (unsigned)Wim) {
        const float* sp = x + (((size_t)b * 32 + cb * 8) * Him + yv) * Wim + xv;
#pragma unroll
        for (int j = 0; j < 8; ++j) hv[j] = (f16)sp[(size_t)j * Him * Wim];
    } else {
#pragma unroll
        for (int j = 0; j < 8; ++j) hv[j] = (f16)0.f;
    }
    *(f16x8*)&xh[(size_t)pxl * 32 + cb * 8] = hv;
}

// ---------------- prep3: weights -> f16 [tap][n][c] XOR-SWIZZLED + BN fold
__global__ __launch_bounds__(256) void prep3_kernel(
    const float* __restrict__ w1_hm, const float* __restrict__ b1_hm,
    const float* __restrict__ g_hm,  const float* __restrict__ be_hm,
    const float* __restrict__ m_hm,  const float* __restrict__ v_hm,
    const float* __restrict__ w1_vec, const float* __restrict__ b1_vec,
    const float* __restrict__ g_vec,  const float* __restrict__ be_vec,
    const float* __restrict__ m_vec,  const float* __restrict__ v_vec,
    void* __restrict__ wreg)
{
    f16* wf = (f16*)wreg;
    float* alpha = (float*)((char*)wreg + WBYTES);
    float* beta  = alpha + 128;

    int e = blockIdx.x * 256 + threadIdx.x;   // 9*128*32 = 36864 exactly
    int rs = e >> 12;          // tap 0..8
    int rem = e & 4095;
    int n = rem >> 5;          // 0..127
    int c = rem & 31;          // 0..31
    float v;
    if (n < 64) v = w1_hm[(n * 32 + c) * 9 + rs];
    else        v = w1_vec[((n - 64) * 32 + c) * 9 + rs];
    int byte = rs * 8192 + n * 64 + c * 2;
    byte ^= (n & 7) << 4;                     // bank swizzle
    wf[byte >> 1] = (f16)v;

    if (e < 128) {
        int nn = e;
        float g, be, m, vv, b1;
        if (nn < 64) { g = g_hm[nn]; be = be_hm[nn]; m = m_hm[nn]; vv = v_hm[nn]; b1 = b1_hm[nn]; }
        else { int j = nn - 64; g = g_vec[j]; be = be_vec[j]; m = m_vec[j]; vv = v_vec[j]; b1 = b1_vec[j]; }
        float a = g * rsqrtf(vv + BN_EPS);
        alpha[nn] = a;
        beta[nn]  = a * (b1 - m) + be;
    }
}

// ---------------- conv6: conv5 geometry, 16 waves/block (wave = 64-px half-row)
// grid: 1024 blocks (8 img x 64 strips x 2 halves), 1024 threads = 16 waves.
// Block tile: 8 rows x 128 px x 128 ch. Wave: row = wv>>1, xseg = wv&1.
__global__ __launch_bounds__(1024, 1) void conv6_kernel(
    const f16* __restrict__ xh, const f16* __restrict__ wsw,
    const float* __restrict__ alpha, const float* __restrict__ beta,
    const float* __restrict__ w2_hm, const float* __restrict__ b2_hm,
    const float* __restrict__ w2_vec, const float* __restrict__ b2_vec,
    float* __restrict__ out)
{
    __shared__ __align__(16) f16 s_w[9 * 128 * 32];     // 73728 B, swizzled
    __shared__ __align__(16) f16 s_in[10 * 130 * 32];   // 83200 B, swizzled

    // XCD-aware bijective block swizzle: XCD k owns image b=k's blocks
    const int hw = blockIdx.x;
    const int logical = (hw & 7) * 128 + (hw >> 3);
    const int b    = logical >> 7;
    const int idx  = logical & 127;
    const int strip = idx >> 1;
    const int half  = idx & 1;
    const int y0  = strip * 8;
    const int x0h = half * 128;

    const int tid  = threadIdx.x;
    const int lane = tid & 63;
    const int wv   = tid >> 6;      // 0..15
    const int row  = wv >> 1;       // 0..7 -> output row y0+row
    const int xseg = wv & 1;        // 0..1 -> 64-px half

    // ---- stage swizzled weights (73728 B = 4608 float4)
    {
        const float4* src = (const float4*)wsw;
        float4* dst = (float4*)s_w;
        for (int i = tid; i < 4608; i += 1024) dst[i] = src[i];
    }
    // ---- stage input strip: padded rows y0..y0+9, padded px x0h..x0h+129
    {
        const char* xb = (const char*)(xh + (size_t)b * PH * (PW * 32));
        char* sb = (char*)s_in;
        for (int i = tid; i < 5200; i += 1024) {       // 10*130*4 16B-chunks
            int rw = i / 520;
            int r2  = i - rw * 520;
            int px  = r2 >> 2;
            int bo  = (r2 & 3) << 4;
            f16x8 v = *(const f16x8*)(xb + (((size_t)(y0 + rw) * PW + (x0h + px)) << 6) + bo);
            int la = ((rw * 130 + px) << 6) + bo;
            la ^= (px & 7) << 4;
            *(f16x8*)(sb + la) = v;
        }
    }
    __syncthreads();

    const int l15 = lane & 15;
    const int khB = (lane >> 4) << 4;                          // 0,16,32,48
    const int sxz = ((l15 << 6) + khB) ^ ((l15 & 7) << 4);     // swizzled B lane offset
    const char* swb = (const char*)s_w;
    const char* sib = (const char*)s_in;

    float* outhm  = out + ((size_t)b * 2) * Him * Wim + (y0 + row) * Wim + x0h;
    float* outvec = out + OFF_VEC + ((size_t)b * 2) * Him * Wim + (y0 + row) * Wim + x0h;

    const int px0s = xseg << 6;

    f32x4 acc[4][8];
#pragma unroll
    for (int pt = 0; pt < 4; ++pt)
#pragma unroll
        for (int nt = 0; nt < 8; ++nt) acc[pt][nt] = (f32x4){0.f, 0.f, 0.f, 0.f};

    // tap loops NOT unrolled: prevents cross-tap hoisting of af/bf (spill source)
#pragma unroll 1
    for (int rr = 0; rr < 3; ++rr) {
#pragma unroll 1
        for (int ss = 0; ss < 3; ++ss) {
            f16x8 af[4];
#pragma unroll
            for (int pt = 0; pt < 4; ++pt) {
                int pxl = px0s + pt * 16 + l15 + ss;
                int la = (((row + rr) * 130 + pxl) << 6) + khB;
                la ^= (pxl & 7) << 4;
                af[pt] = *(const f16x8*)(sib + la);
            }
            const char* wtap = swb + (rr * 3 + ss) * 8192 + sxz;
#pragma unroll
            for (int nt = 0; nt < 8; ++nt) {
                f16x8 bf = *(const f16x8*)(wtap + nt * 1024);
                acc[0][nt] = __builtin_amdgcn_mfma_f32_16x16x32_f16(af[0], bf, acc[0][nt], 0, 0, 0);
                acc[1][nt] = __builtin_amdgcn_mfma_f32_16x16x32_f16(af[1], bf, acc[1][nt], 0, 0, 0);
                acc[2][nt] = __builtin_amdgcn_mfma_f32_16x16x32_f16(af[2], bf, acc[2][nt], 0, 0, 0);
                acc[3][nt] = __builtin_amdgcn_mfma_f32_16x16x32_f16(af[3], bf, acc[3][nt], 0, 0, 0);
            }
        }
    }

    // epilogue: constants loaded HERE (outside MFMA live range)
    float al[8], bt[8], wa[8], wb[8];
#pragma unroll
    for (int nt = 0; nt < 8; ++nt) {
        int ch = nt * 16 + l15;
        al[nt] = alpha[ch];
        bt[nt] = beta[ch];
        int c6 = ch & 63;
        const float* w2 = (ch < 64) ? w2_hm : w2_vec;
        wa[nt] = w2[c6];
        wb[nt] = w2[64 + c6];
    }
    const float bh0 = b2_hm[0], bh1 = b2_hm[1], bv0 = b2_vec[0], bv1 = b2_vec[1];

#pragma unroll
    for (int pt = 0; pt < 4; ++pt) {
#pragma unroll
        for (int q = 0; q < 4; ++q) {
            float s0 = 0.f, s1 = 0.f, s2 = 0.f, s3 = 0.f;
#pragma unroll
            for (int nt = 0; nt < 8; ++nt) {
                float h = fmaf(al[nt], acc[pt][nt][q], bt[nt]);
                h = fmaxf(h, 0.f);
                if (nt < 4) { s0 = fmaf(wa[nt], h, s0); s1 = fmaf(wb[nt], h, s1); }
                else        { s2 = fmaf(wa[nt], h, s2); s3 = fmaf(wb[nt], h, s3); }
            }
#pragma unroll
            for (int off = 1; off < 16; off <<= 1) {
                s0 += __shfl_xor(s0, off);
                s1 += __shfl_xor(s1, off);
                s2 += __shfl_xor(s2, off);
                s3 += __shfl_xor(s3, off);
            }
            int px = px0s + pt * 16 + ((lane >> 4) << 2) + q;
            if (l15 == 0) {
                outhm[px] = 1.f / (1.f + expf(-(s0 + bh0)));
            } else if (l15 == 1) {
                outhm[Him * Wim + px] = 1.f / (1.f + expf(-(s1 + bh1)));
            } else if (l15 == 2) {
                outvec[px] = s2 + bv0;
            } else if (l15 == 3) {
                outvec[Him * Wim + px] = s3 + bv1;
            }
        }
    }
}

// =====================================================================
// FALLBACK PATH (round-2 kernels, used only if ws_size < WS_NEED)
// =====================================================================

__global__ __launch_bounds__(256) void prep_fb_kernel(
    const float* __restrict__ w1_hm, const float* __restrict__ b1_hm,
    const float* __restrict__ g_hm,  const float* __restrict__ be_hm,
    const float* __restrict__ m_hm,  const float* __restrict__ v_hm,
    const float* __restrict__ w1_vec, const float* __restrict__ b1_vec,
    const float* __restrict__ g_vec,  const float* __restrict__ be_vec,
    const float* __restrict__ m_vec,  const float* __restrict__ v_vec,
    void* __restrict__ wsv)
{
    f16* wf = (f16*)wsv;
    float* alpha = (float*)((char*)wsv + WS_WBYTES);
    float* beta  = alpha + 128;
    int e = blockIdx.x * 256 + threadIdx.x;
    int rs = e >> 12;
    int rem = e & 4095;
    int n = rem >> 5;
    int c = rem & 31;
    float v;
    if (n < 64) v = w1_hm[(n * 32 + c) * 9 + rs];
    else        v = w1_vec[((n - 64) * 32 + c) * 9 + rs];
    wf[e] = (f16)v;
    if (e < 128) {
        int nn = e;
        float g, be, m, vv, b1;
        if (nn < 64) { g = g_hm[nn]; be = be_hm[nn]; m = m_hm[nn]; vv = v_hm[nn]; b1 = b1_hm[nn]; }
        else { int j = nn - 64; g = g_vec[j]; be = be_vec[j]; m = m_vec[j]; vv = v_vec[j]; b1 = b1_vec[j]; }
        float a = g * rsqrtf(vv + BN_EPS);
        alpha[nn] = a;
        beta[nn]  = a * (b1 - m) + be;
    }
}

__global__ __launch_bounds__(256, 1) void conv_fb_kernel(
    const float* __restrict__ x, const void* __restrict__ wsv,
    const float* __restrict__ w2_hm, const float* __restrict__ b2_hm,
    const float* __restrict__ w2_vec, const float* __restrict__ b2_vec,
    float* __restrict__ out)
{
    __shared__ __align__(16) f16 s_x[3 * XCOLS * XSTR];
    __shared__ __align__(16) f16 s_w[9 * 128 * 32];

    const int bid = blockIdx.x;
    const int y = bid & 511;
    const int b = bid >> 9;
    const int tid = threadIdx.x;
    const int lane = tid & 63;
    const int wv = tid >> 6;

    {
        const float4* src = (const float4*)wsv;
        float4* dst = (float4*)s_w;
#pragma unroll
        for (int i = 0; i < 18; ++i) dst[tid + 256 * i] = src[tid + 256 * i];
    }
    {
        const float* xb = x + (size_t)b * 32 * Him * Wim;
#pragma unroll 1
        for (int g = 0; g < 12; ++g) {
            int r  = g >> 2;
            int cb = (g & 3) << 3;
            int gy = y + r - 1;
            bool rowok = (gy >= 0) && (gy < Him);
            {
                int col = tid;
                int gx = col - 1;
                bool ok = rowok && (gx >= 0);
                f16x8 hv;
#pragma unroll
                for (int j = 0; j < 8; ++j) {
                    float v = ok ? xb[(size_t)(cb + j) * (Him * Wim) + gy * Wim + gx] : 0.f;
                    hv[j] = (f16)v;
                }
                *(f16x8*)&s_x[(r * XCOLS + col) * XSTR + cb] = hv;
            }
            if (tid < 2) {
                int col = 256 + tid;
                int gx = col - 1;
                bool ok = rowok && (gx < Wim);
                f16x8 hv;
#pragma unroll
                for (int j = 0; j < 8; ++j) {
                    float v = ok ? xb[(size_t)(cb + j) * (Him * Wim) + gy * Wim + gx] : 0.f;
                    hv[j] = (f16)v;
                }
                *(f16x8*)&s_x[(r * XCOLS + col) * XSTR + cb] = hv;
            }
        }
    }
    __syncthreads();

    const int px0 = wv * 64;
    const int l15 = lane & 15;
    const int khalf = (lane >> 4) << 3;

    f32x4 acc[4][8];
#pragma unroll
    for (int pt = 0; pt < 4; ++pt)
#pragma unroll
        for (int nt = 0; nt < 8; ++nt) acc[pt][nt] = (f32x4){0.f, 0.f, 0.f, 0.f};

#pragma unroll 1
    for (int rs = 0; rs < 9; ++rs) {
        const int rr = rs / 3, ss = rs % 3;
        f16x8 af[4];
#pragma unroll
        for (int pt = 0; pt < 4; ++pt) {
            int col = px0 + pt * 16 + l15 + ss;
            af[pt] = *(const f16x8*)&s_x[(rr * XCOLS + col) * XSTR + khalf];
        }
#pragma unroll
        for (int nt = 0; nt < 8; ++nt) {
            f16x8 bf = *(const f16x8*)&s_w[rs * 4096 + (nt * 16 + l15) * 32 + khalf];
            acc[0][nt] = __builtin_amdgcn_mfma_f32_16x16x32_f16(af[0], bf, acc[0][nt], 0, 0, 0);
            acc[1][nt] = __builtin_amdgcn_mfma_f32_16x16x32_f16(af[1], bf, acc[1][nt], 0, 0, 0);
            acc[2][nt] = __builtin_amdgcn_mfma_f32_16x16x32_f16(af[2], bf, acc[2][nt], 0, 0, 0);
            acc[3][nt] = __builtin_amdgcn_mfma_f32_16x16x32_f16(af[3], bf, acc[3][nt], 0, 0, 0);
        }
    }

    const float* alpha = (const float*)((const char*)wsv + WS_WBYTES);
    const float* beta  = alpha + 128;
    float al[8], bt[8], wa[8], wb[8];
#pragma unroll
    for (int nt = 0; nt < 8; ++nt) {
        int ch = nt * 16 + l15;
        al[nt] = alpha[ch];
        bt[nt] = beta[ch];
        int c6 = ch & 63;
        const float* w2 = (ch < 64) ? w2_hm : w2_vec;
        wa[nt] = w2[c6];
        wb[nt] = w2[64 + c6];
    }
    const float bh0 = b2_hm[0], bh1 = b2_hm[1], bv0 = b2_vec[0], bv1 = b2_vec[1];

    float* outhm  = out + ((size_t)b * 2) * Him * Wim + y * Wim;
    float* outvec = out + OFF_VEC + ((size_t)b * 2) * Him * Wim + y * Wim;

#pragma unroll
    for (int pt = 0; pt < 4; ++pt) {
#pragma unroll
        for (int q = 0; q < 4; ++q) {
            float s0 = 0.f, s1 = 0.f, s2 = 0.f, s3 = 0.f;
#pragma unroll
            for (int nt = 0; nt < 8; ++nt) {
                float h = fmaf(al[nt], acc[pt][nt][q], bt[nt]);
                h = fmaxf(h, 0.f);
                if (nt < 4) { s0 = fmaf(wa[nt], h, s0); s1 = fmaf(wb[nt], h, s1); }
                else        { s2 = fmaf(wa[nt], h, s2); s3 = fmaf(wb[nt], h, s3); }
            }
#pragma unroll
            for (int off = 1; off < 16; off <<= 1) {
                s0 += __shfl_xor(s0, off);
                s1 += __shfl_xor(s1, off);
                s2 += __shfl_xor(s2, off);
                s3 += __shfl_xor(s3, off);
            }
            int px = px0 + pt * 16 + ((lane >> 4) << 2) + q;
            if (l15 == 0) {
                outhm[px] = 1.f / (1.f + expf(-(s0 + bh0)));
            } else if (l15 == 1) {
                outhm[Him * Wim + px] = 1.f / (1.f + expf(-(s1 + bh1)));
            } else if (l15 == 2) {
                outvec[px] = s2 + bv0;
            } else if (l15 == 3) {
                outvec[Him * Wim + px] = s3 + bv1;
            }
        }
    }
}

// =====================================================================
// peak extraction: 1024 threads/block, 2 barriers/iteration
// =====================================================================
__global__ __launch_bounds__(1024) void peak_kernel(float* __restrict__ out)
{
    __shared__ float rowval[512];
    __shared__ int   rowcol[512];
    __shared__ int   sbx[NPK], sby[NPK];
    __shared__ int   s_grow;
    __shared__ int   ppx[NPK], ppy[NPK];

    int m = blockIdx.x;
    const float* hm = out + (size_t)m * (Him * Wim);
    int tid  = threadIdx.x;
    int lane = tid & 63;
    int wv   = tid >> 6;       // 0..15

    if (tid < NPK) { ppx[tid] = 0; ppy[tid] = 0; }

    // phase A: per-row (max, first argmax col); wave per row, 32 rows/wave
#pragma unroll 4
    for (int row = wv; row < 512; row += 16) {
        float4 v4 = *reinterpret_cast<const float4*>(hm + row * 256 + (lane << 2));
        float bv = v4.x; int bc = lane << 2;
        if (v4.y > bv) { bv = v4.y; bc = (lane << 2) + 1; }
        if (v4.z > bv) { bv = v4.z; bc = (lane << 2) + 2; }
        if (v4.w > bv) { bv = v4.w; bc = (lane << 2) + 3; }
#pragma unroll
        for (int off = 32; off; off >>= 1) {
            float ov = __shfl_xor(bv, off);
            int   oc = __shfl_xor(bc, off);
            if (ov > bv || (ov == bv && oc < bc)) { bv = ov; bc = oc; }
        }
        if (lane == 0) { rowval[row] = bv; rowcol[row] = bc; }
    }
    __syncthreads();

    for (int it = 0; it < NPK; ++it) {
        // wave0: global argmax over 512 rows (first-row tie-break)
        if (wv == 0) {
            float bv = rowval[lane]; int br = lane;
#pragma unroll
            for (int k = 1; k < 8; ++k) {
                float v = rowval[lane + 64 * k];
                if (v > bv) { bv = v; br = lane + 64 * k; }
            }
#pragma unroll
            for (int off = 32; off; off >>= 1) {
                float ov = __shfl_xor(bv, off);
                int   orr = __shfl_xor(br, off);
                if (ov > bv || (ov == bv && orr < br)) { bv = ov; br = orr; }
            }
            if (lane == 0) {
                if (bv > PTHRESH) {
                    int gc = rowcol[br];
                    ppx[it] = gc; ppy[it] = br;
                    sbx[it] = gc; sby[it] = br;
                    s_grow  = br;
                } else {
                    s_grow = -1;
                }
            }
        }
        __syncthreads();
        int grow = s_grow;
        if (grow < 0) break;   // uniform: all later peaks are (0,0), already zeroed

        // 11 waves rescan one row each with box exclusion
        if (wv < 11) {
            int row = grow - RAD + wv;
            if (row >= 0 && row < 512) {
                int nb = it + 1;
                float4 v4 = *reinterpret_cast<const float4*>(hm + row * 256 + (lane << 2));
                float vals[4] = { v4.x, v4.y, v4.z, v4.w };
                float bv2 = -1.f; int bc2 = 0;
#pragma unroll
                for (int q = 0; q < 4; ++q) {
                    int col = (lane << 2) + q;
                    float val = vals[q];
                    for (int i = 0; i < nb; ++i) {
                        int dy = row - sby[i]; if (dy < 0) dy = -dy;
                        int dx = col - sbx[i]; if (dx < 0) dx = -dx;
                        if (dy <= RAD && dx <= RAD) { val = 0.f; break; }
                    }
                    if (val > bv2) { bv2 = val; bc2 = col; }
                }
#pragma unroll
                for (int off = 32; off; off >>= 1) {
                    float ov = __shfl_xor(bv2, off);
                    int   oc = __shfl_xor(bc2, off);
                    if (ov > bv2 || (ov == bv2 && oc < bc2)) { bv2 = ov; bc2 = oc; }
                }
                if (lane == 0) { rowval[row] = bv2; rowcol[row] = bc2; }
            }
        }
        __syncthreads();
    }
    __syncthreads();

    // ordering: stable sort by y descending, invalid -> (0,0) at end
    if (tid == 0) {
        float key[NPK]; int ord[NPK];
        for (int i = 0; i < NPK; ++i) {
            int valid = (ppx[i] + ppy[i]) != 0;
            key[i] = valid ? (float)ppy[i] : -3.4e38f;
            ord[i] = i;
        }
        for (int i = 1; i < NPK; ++i) {
            int oi = ord[i]; float ki = key[oi];
            int j = i - 1;
            while (j >= 0 && key[ord[j]] < ki) { ord[j + 1] = ord[j]; --j; }
            ord[j + 1] = oi;
        }
        int bb = m >> 1, which = m & 1;
        float* dst = out + (which ? OFF_LO : OFF_UP) + bb * (NPK * 2);
        for (int i = 0; i < NPK; ++i) {
            int src = ord[i];
            int valid = (ppx[src] + ppy[src]) != 0;
            dst[i * 2 + 0] = valid ? (float)ppx[src] : 0.f;
            dst[i * 2 + 1] = valid ? (float)ppy[src] : 0.f;
        }
    }
}

__global__ __launch_bounds__(320) void mid_kernel(float* __restrict__ out)
{
    int t = threadIdx.x;
    if (t < Bn * NPK * 2)
        out[OFF_MID + t] = 0.5f * (out[OFF_UP + t] + out[OFF_LO + t]);
}

extern "C" void kernel_launch(void* const* d_in, const int* in_sizes, int n_in,
                              void* d_out, int out_size, void* d_ws, size_t ws_size,
                              hipStream_t stream)
{
    const float* x      = (const float*)d_in[0];
    const float* w1_hm  = (const float*)d_in[1];
    const float* b1_hm  = (const float*)d_in[2];
    const float* g_hm   = (const float*)d_in[3];
    const float* be_hm  = (const float*)d_in[4];
    const float* m_hm   = (const float*)d_in[5];
    const float* v_hm   = (const float*)d_in[6];
    const float* w2_hm  = (const float*)d_in[7];
    const float* b2_hm  = (const float*)d_in[8];
    const float* w1_vec = (const float*)d_in[9];
    const float* b1_vec = (const float*)d_in[10];
    const float* g_vec  = (const float*)d_in[11];
    const float* be_vec = (const float*)d_in[12];
    const float* m_vec  = (const float*)d_in[13];
    const float* v_vec  = (const float*)d_in[14];
    const float* w2_vec = (const float*)d_in[15];
    const float* b2_vec = (const float*)d_in[16];

    float* out = (float*)d_out;

    if (ws_size >= (size_t)WS_NEED) {
        f16*  xh   = (f16*)d_ws;
        char* wreg = (char*)d_ws + XH_BYTES;
        const float* alpha = (const float*)(wreg + WBYTES);
        const float* beta  = alpha + 128;

        xform_kernel<<<(Bn * PH * PW * 4 + 255) / 256, 256, 0, stream>>>(x, xh);
        prep3_kernel<<<144, 256, 0, stream>>>(
            w1_hm, b1_hm, g_hm, be_hm, m_hm, v_hm,
            w1_vec, b1_vec, g_vec, be_vec, m_vec, v_vec, wreg);
        conv6_kernel<<<1024, 1024, 0, stream>>>(
            xh, (const f16*)wreg, alpha, beta,
            w2_hm, b2_hm, w2_vec, b2_vec, out);
    } else {
        prep_fb_kernel<<<144, 256, 0, stream>>>(
            w1_hm, b1_hm, g_hm, be_hm, m_hm, v_hm,
            w1_vec, b1_vec, g_vec, be_vec, m_vec, v_vec, d_ws);
        conv_fb_kernel<<<Bn * Him, 256, 0, stream>>>(
            x, d_ws, w2_hm, b2_hm, w2_vec, b2_vec, out);
    }

    peak_kernel<<<Bn * 2, 1024, 0, stream>>>(out);

    mid_kernel<<<1, 320, 0, stream>>>(out);
}

// Round 8
// 260.119 us; speedup vs baseline: 3.1819x; 3.1819x over previous
//
#include <hip/hip_runtime.h>

typedef _Float16 f16;
typedef _Float16 f16x8 __attribute__((ext_vector_type(8)));
typedef float f32x4 __attribute__((ext_vector_type(4)));

#define Bn 8
#define Him 512
#define Wim 256
#define NPK 18
#define RAD 5
#define PTHRESH 0.1f
#define BN_EPS 1e-5f

// d_out layout (floats)
#define SZ_HM   (Bn*2*Him*Wim)
#define OFF_UP  (SZ_HM)
#define OFF_LO  (OFF_UP + Bn*NPK*2)
#define OFF_MID (OFF_LO + Bn*NPK*2)
#define OFF_VEC (OFF_MID + Bn*NPK*2)

// ---- fast-path ws layout: xh padded NHWC f16, then swizzled weights, then f32 tables
#define PH (Him + 2)                 // 514
#define PW (Wim + 2)                 // 258
#define XH_ELT ((size_t)Bn * PH * PW * 32)
#define XH_BYTES (XH_ELT * 2)        // 67,897,344
#define WBYTES 73728
#define WS_NEED (XH_BYTES + WBYTES + 4096)

// ---- fallback (round-2) ws layout
#define WS_WBYTES 73728
#define XCOLS 258
#define XSTR  40

// =====================================================================
// FAST PATH
// =====================================================================

// ---------------- xform: x [8][32][512][256] f32 -> xh [8][514][258][32] f16 (zero halo)
__global__ __launch_bounds__(256) void xform_kernel(
    const float* __restrict__ x, f16* __restrict__ xh)
{
    int e = blockIdx.x * 256 + threadIdx.x;          // 4,243,584 total
    if (e >= Bn * PH * PW * 4) return;
    int cb  = e & 3;                                  // 8-ch chunk
    int pxl = e >> 2;                                 // padded pixel linear
    int b   = pxl / (PH * PW);
    int rem = pxl - b * (PH * PW);
    int yy  = rem / PW;
    int xx  = rem - yy * PW;
    int yv = yy - 1, xv = xx - 1;
    f16x8 hv;
    if ((unsigned)yv < (unsigned)Him && (unsigned)xv < (unsigned)Wim) {
        const float* sp = x + (((size_t)b * 32 + cb * 8) * Him + yv) * Wim + xv;
#pragma unroll
        for (int j = 0; j < 8; ++j) hv[j] = (f16)sp[(size_t)j * Him * Wim];
    } else {
#pragma unroll
        for (int j = 0; j < 8; ++j) hv[j] = (f16)0.f;
    }
    *(f16x8*)&xh[(size_t)pxl * 32 + cb * 8] = hv;
}

// ---------------- prep4: weights -> f16 [tap][n][c] XOR-SWIZZLED, alpha FOLDED; f32 tables
__global__ __launch_bounds__(256) void prep4_kernel(
    const float* __restrict__ w1_hm, const float* __restrict__ b1_hm,
    const float* __restrict__ g_hm,  const float* __restrict__ be_hm,
    const float* __restrict__ m_hm,  const float* __restrict__ v_hm,
    const float* __restrict__ w1_vec, const float* __restrict__ b1_vec,
    const float* __restrict__ g_vec,  const float* __restrict__ be_vec,
    const float* __restrict__ m_vec,  const float* __restrict__ v_vec,
    const float* __restrict__ w2_hm,  const float* __restrict__ w2_vec,
    void* __restrict__ wreg)
{
    f16* wf = (f16*)wreg;
    float* btf = (float*)((char*)wreg + WBYTES);   // beta folded (alpha*(b1-m)+be)
    float* waf = btf + 128;                        // w2 row 0 per channel
    float* wbf = btf + 256;                        // w2 row 1 per channel

    int e = blockIdx.x * 256 + threadIdx.x;   // 9*128*32 = 36864 exactly
    int rs = e >> 12;          // tap 0..8
    int rem = e & 4095;
    int n = rem >> 5;          // 0..127
    int c = rem & 31;          // 0..31

    float g, vv, v;
    if (n < 64) { g = g_hm[n]; vv = v_hm[n]; v = w1_hm[(n * 32 + c) * 9 + rs]; }
    else { int j = n - 64; g = g_vec[j]; vv = v_vec[j]; v = w1_vec[(j * 32 + c) * 9 + rs]; }
    float al = g * rsqrtf(vv + BN_EPS);
    int byte = rs * 8192 + n * 64 + c * 2;
    byte ^= (n & 7) << 4;                     // bank swizzle
    wf[byte >> 1] = (f16)(v * al);            // alpha folded into weight

    if (e < 128) {
        int nn = e;
        float gg, be, m, vvv, b1;
        if (nn < 64) { gg = g_hm[nn]; be = be_hm[nn]; m = m_hm[nn]; vvv = v_hm[nn]; b1 = b1_hm[nn]; }
        else { int j = nn - 64; gg = g_vec[j]; be = be_vec[j]; m = m_vec[j]; vvv = v_vec[j]; b1 = b1_vec[j]; }
        float a = gg * rsqrtf(vvv + BN_EPS);
        btf[nn] = a * (b1 - m) + be;
        if (nn < 64) { waf[nn] = w2_hm[nn]; wbf[nn] = w2_hm[64 + nn]; }
        else { int j = nn - 64; waf[nn] = w2_vec[j]; wbf[nn] = w2_vec[64 + j]; }
    }
}

// ---------------- conv7: conv5 geometry, swapped MFMA operands + lean epilogue
// grid: 1024 blocks (8 img x 64 strips x 2 halves), 512 threads = 8 waves.
// Block tile: 8 rows x 128 px x 128 ch. Wave = 1 row, 2 xsegs of 64 px.
// MFMA: A = weights (M=out-ch), B = pixels (N=px) -> D[ch][px], px on lane&15.
__global__ __launch_bounds__(512, 2) void conv7_kernel(
    const f16* __restrict__ xh, const f16* __restrict__ wsw,
    const float* __restrict__ btf, const float* __restrict__ waf,
    const float* __restrict__ wbf,
    const float* __restrict__ b2_hm, const float* __restrict__ b2_vec,
    float* __restrict__ out)
{
    __shared__ __align__(16) f16 s_w[9 * 128 * 32];     // 73728 B, swizzled
    __shared__ __align__(16) f16 s_in[10 * 130 * 32];   // 83200 B, swizzled

    // XCD-aware bijective block swizzle: XCD k owns image b=k's blocks
    const int hw = blockIdx.x;
    const int logical = (hw & 7) * 128 + (hw >> 3);
    const int b    = logical >> 7;
    const int idx  = logical & 127;
    const int strip = idx >> 1;
    const int half  = idx & 1;
    const int y0  = strip * 8;
    const int x0h = half * 128;

    const int tid  = threadIdx.x;
    const int lane = tid & 63;
    const int wv   = tid >> 6;      // 0..7 -> output row y0+wv

    // ---- stage swizzled weights (73728 B = 4608 float4, 9 rounds)
    {
        const float4* src = (const float4*)wsw;
        float4* dst = (float4*)s_w;
#pragma unroll
        for (int i = 0; i < 9; ++i) dst[tid + 512 * i] = src[tid + 512 * i];
    }
    // ---- stage input strip: padded rows y0..y0+9, padded px x0h..x0h+129
    {
        const char* xb = (const char*)(xh + (size_t)b * PH * (PW * 32));
        char* sb = (char*)s_in;
        for (int i = tid; i < 5200; i += 512) {       // 10*130*4 16B-chunks
            int row = i / 520;
            int r2  = i - row * 520;
            int px  = r2 >> 2;
            int bo  = (r2 & 3) << 4;
            f16x8 v = *(const f16x8*)(xb + (((size_t)(y0 + row) * PW + (x0h + px)) << 6) + bo);
            int la = ((row * 130 + px) << 6) + bo;
            la ^= (px & 7) << 4;
            *(f16x8*)(sb + la) = v;
        }
    }
    __syncthreads();

    const int l15 = lane & 15;
    const int g   = lane >> 4;                                 // lane group 0..3
    const int khB = g << 4;                                    // k-half byte offset
    const int sxz = ((l15 << 6) + khB) ^ ((l15 & 7) << 4);     // swizzled W lane offset
    const char* swb = (const char*)s_w;
    const char* sib = (const char*)s_in;

    float* outhm  = out + ((size_t)b * 2) * Him * Wim + (y0 + wv) * Wim + x0h;
    float* outvec = out + OFF_VEC + ((size_t)b * 2) * Him * Wim + (y0 + wv) * Wim + x0h;

#pragma unroll 1
    for (int xseg = 0; xseg < 2; ++xseg) {
        const int px0s = xseg << 6;

        f32x4 acc[8][4];   // [ch-tile][px-tile]
#pragma unroll
        for (int ct = 0; ct < 8; ++ct)
#pragma unroll
            for (int nt = 0; nt < 4; ++nt) acc[ct][nt] = (f32x4){0.f, 0.f, 0.f, 0.f};

        // tap loops NOT unrolled: prevents cross-tap hoisting (spill source)
#pragma unroll 1
        for (int rr = 0; rr < 3; ++rr) {
#pragma unroll 1
            for (int ss = 0; ss < 3; ++ss) {
                f16x8 af[4];
#pragma unroll
                for (int nt = 0; nt < 4; ++nt) {
                    int pxl = px0s + nt * 16 + l15 + ss;
                    int la = (((wv + rr) * 130 + pxl) << 6) + khB;
                    la ^= (pxl & 7) << 4;
                    af[nt] = *(const f16x8*)(sib + la);
                }
                const char* wtap = swb + (rr * 3 + ss) * 8192 + sxz;
#pragma unroll
                for (int ct = 0; ct < 8; ++ct) {
                    f16x8 wfr = *(const f16x8*)(wtap + ct * 1024);
                    acc[ct][0] = __builtin_amdgcn_mfma_f32_16x16x32_f16(wfr, af[0], acc[ct][0], 0, 0, 0);
                    acc[ct][1] = __builtin_amdgcn_mfma_f32_16x16x32_f16(wfr, af[1], acc[ct][1], 0, 0, 0);
                    acc[ct][2] = __builtin_amdgcn_mfma_f32_16x16x32_f16(wfr, af[2], acc[ct][2], 0, 0, 0);
                    acc[ct][3] = __builtin_amdgcn_mfma_f32_16x16x32_f16(wfr, af[3], acc[ct][3], 0, 0, 0);
                }
            }
        }

        // ---- epilogue: lane holds D[ch = ct*16 + g*4 + q][px = px0s + nt*16 + l15]
        // per-lane weighted partial over its 32 channels, then 2-step butterfly over g.
        float s[4][4];     // [px-tile][out 0..3]
#pragma unroll
        for (int nt = 0; nt < 4; ++nt)
#pragma unroll
            for (int o = 0; o < 4; ++o) s[nt][o] = 0.f;

        const int cb0 = g << 2;   // channel offset within ch-tile
#pragma unroll
        for (int ct = 0; ct < 8; ++ct) {
            const float4 bt4 = *(const float4*)&btf[ct * 16 + cb0];
            const float4 wa4 = *(const float4*)&waf[ct * 16 + cb0];
            const float4 wb4 = *(const float4*)&wbf[ct * 16 + cb0];
            float btq[4] = { bt4.x, bt4.y, bt4.z, bt4.w };
            float waq[4] = { wa4.x, wa4.y, wa4.z, wa4.w };
            float wbq[4] = { wb4.x, wb4.y, wb4.z, wb4.w };
#pragma unroll
            for (int nt = 0; nt < 4; ++nt) {
#pragma unroll
                for (int q = 0; q < 4; ++q) {
                    float h = fmaxf(acc[ct][nt][q] + btq[q], 0.f);
                    if (ct < 4) {
                        s[nt][0] = fmaf(waq[q], h, s[nt][0]);
                        s[nt][1] = fmaf(wbq[q], h, s[nt][1]);
                    } else {
                        s[nt][2] = fmaf(waq[q], h, s[nt][2]);
                        s[nt][3] = fmaf(wbq[q], h, s[nt][3]);
                    }
                }
            }
        }
        // reduce over the 4 lane-groups (xor 16, xor 32)
#pragma unroll
        for (int nt = 0; nt < 4; ++nt)
#pragma unroll
            for (int o = 0; o < 4; ++o) {
                s[nt][o] += __shfl_xor(s[nt][o], 16);
                s[nt][o] += __shfl_xor(s[nt][o], 32);
            }

        const float bh0 = b2_hm[0], bh1 = b2_hm[1], bv0 = b2_vec[0], bv1 = b2_vec[1];
        if (g == 0) {
#pragma unroll
            for (int nt = 0; nt < 4; ++nt) {
                int px = px0s + nt * 16 + l15;
                float e = __expf(-(s[nt][0] + bh0));
                outhm[px] = 1.f / (1.f + e);
            }
        } else if (g == 1) {
#pragma unroll
            for (int nt = 0; nt < 4; ++nt) {
                int px = px0s + nt * 16 + l15;
                float e = __expf(-(s[nt][1] + bh1));
                outhm[Him * Wim + px] = 1.f / (1.f + e);
            }
        } else if (g == 2) {
#pragma unroll
            for (int nt = 0; nt < 4; ++nt) {
                int px = px0s + nt * 16 + l15;
                outvec[px] = s[nt][2] + bv0;
            }
        } else {
#pragma unroll
            for (int nt = 0; nt < 4; ++nt) {
                int px = px0s + nt * 16 + l15;
                outvec[Him * Wim + px] = s[nt][3] + bv1;
            }
        }
    }
}

// =====================================================================
// FALLBACK PATH (round-2 kernels, used only if ws_size < WS_NEED)
// =====================================================================

__global__ __launch_bounds__(256) void prep_fb_kernel(
    const float* __restrict__ w1_hm, const float* __restrict__ b1_hm,
    const float* __restrict__ g_hm,  const float* __restrict__ be_hm,
    const float* __restrict__ m_hm,  const float* __restrict__ v_hm,
    const float* __restrict__ w1_vec, const float* __restrict__ b1_vec,
    const float* __restrict__ g_vec,  const float* __restrict__ be_vec,
    const float* __restrict__ m_vec,  const float* __restrict__ v_vec,
    void* __restrict__ wsv)
{
    f16* wf = (f16*)wsv;
    float* alpha = (float*)((char*)wsv + WS_WBYTES);
    float* beta  = alpha + 128;
    int e = blockIdx.x * 256 + threadIdx.x;
    int rs = e >> 12;
    int rem = e & 4095;
    int n = rem >> 5;
    int c = rem & 31;
    float v;
    if (n < 64) v = w1_hm[(n * 32 + c) * 9 + rs];
    else        v = w1_vec[((n - 64) * 32 + c) * 9 + rs];
    wf[e] = (f16)v;
    if (e < 128) {
        int nn = e;
        float g, be, m, vv, b1;
        if (nn < 64) { g = g_hm[nn]; be = be_hm[nn]; m = m_hm[nn]; vv = v_hm[nn]; b1 = b1_hm[nn]; }
        else { int j = nn - 64; g = g_vec[j]; be = be_vec[j]; m = m_vec[j]; vv = v_vec[j]; b1 = b1_vec[j]; }
        float a = g * rsqrtf(vv + BN_EPS);
        alpha[nn] = a;
        beta[nn]  = a * (b1 - m) + be;
    }
}

__global__ __launch_bounds__(256, 1) void conv_fb_kernel(
    const float* __restrict__ x, const void* __restrict__ wsv,
    const float* __restrict__ w2_hm, const float* __restrict__ b2_hm,
    const float* __restrict__ w2_vec, const float* __restrict__ b2_vec,
    float* __restrict__ out)
{
    __shared__ __align__(16) f16 s_x[3 * XCOLS * XSTR];
    __shared__ __align__(16) f16 s_w[9 * 128 * 32];

    const int bid = blockIdx.x;
    const int y = bid & 511;
    const int b = bid >> 9;
    const int tid = threadIdx.x;
    const int lane = tid & 63;
    const int wv = tid >> 6;

    {
        const float4* src = (const float4*)wsv;
        float4* dst = (float4*)s_w;
#pragma unroll
        for (int i = 0; i < 18; ++i) dst[tid + 256 * i] = src[tid + 256 * i];
    }
    {
        const float* xb = x + (size_t)b * 32 * Him * Wim;
#pragma unroll 1
        for (int g = 0; g < 12; ++g) {
            int r  = g >> 2;
            int cb = (g & 3) << 3;
            int gy = y + r - 1;
            bool rowok = (gy >= 0) && (gy < Him);
            {
                int col = tid;
                int gx = col - 1;
                bool ok = rowok && (gx >= 0);
                f16x8 hv;
#pragma unroll
                for (int j = 0; j < 8; ++j) {
                    float v = ok ? xb[(size_t)(cb + j) * (Him * Wim) + gy * Wim + gx] : 0.f;
                    hv[j] = (f16)v;
                }
                *(f16x8*)&s_x[(r * XCOLS + col) * XSTR + cb] = hv;
            }
            if (tid < 2) {
                int col = 256 + tid;
                int gx = col - 1;
                bool ok = rowok && (gx < Wim);
                f16x8 hv;
#pragma unroll
                for (int j = 0; j < 8; ++j) {
                    float v = ok ? xb[(size_t)(cb + j) * (Him * Wim) + gy * Wim + gx] : 0.f;
                    hv[j] = (f16)v;
                }
                *(f16x8*)&s_x[(r * XCOLS + col) * XSTR + cb] = hv;
            }
        }
    }
    __syncthreads();

    const int px0 = wv * 64;
    const int l15 = lane & 15;
    const int khalf = (lane >> 4) << 3;

    f32x4 acc[4][8];
#pragma unroll
    for (int pt = 0; pt < 4; ++pt)
#pragma unroll
        for (int nt = 0; nt < 8; ++nt) acc[pt][nt] = (f32x4){0.f, 0.f, 0.f, 0.f};

#pragma unroll 1
    for (int rs = 0; rs < 9; ++rs) {
        const int rr = rs / 3, ss = rs % 3;
        f16x8 af[4];
#pragma unroll
        for (int pt = 0; pt < 4; ++pt) {
            int col = px0 + pt * 16 + l15 + ss;
            af[pt] = *(const f16x8*)&s_x[(rr * XCOLS + col) * XSTR + khalf];
        }
#pragma unroll
        for (int nt = 0; nt < 8; ++nt) {
            f16x8 bf = *(const f16x8*)&s_w[rs * 4096 + (nt * 16 + l15) * 32 + khalf];
            acc[0][nt] = __builtin_amdgcn_mfma_f32_16x16x32_f16(af[0], bf, acc[0][nt], 0, 0, 0);
            acc[1][nt] = __builtin_amdgcn_mfma_f32_16x16x32_f16(af[1], bf, acc[1][nt], 0, 0, 0);
            acc[2][nt] = __builtin_amdgcn_mfma_f32_16x16x32_f16(af[2], bf, acc[2][nt], 0, 0, 0);
            acc[3][nt] = __builtin_amdgcn_mfma_f32_16x16x32_f16(af[3], bf, acc[3][nt], 0, 0, 0);
        }
    }

    const float* alpha = (const float*)((const char*)wsv + WS_WBYTES);
    const float* beta  = alpha + 128;
    float al[8], bt[8], wa[8], wb[8];
#pragma unroll
    for (int nt = 0; nt < 8; ++nt) {
        int ch = nt * 16 + l15;
        al[nt] = alpha[ch];
        bt[nt] = beta[ch];
        int c6 = ch & 63;
        const float* w2 = (ch < 64) ? w2_hm : w2_vec;
        wa[nt] = w2[c6];
        wb[nt] = w2[64 + c6];
    }
    const float bh0 = b2_hm[0], bh1 = b2_hm[1], bv0 = b2_vec[0], bv1 = b2_vec[1];

    float* outhm  = out + ((size_t)b * 2) * Him * Wim + y * Wim;
    float* outvec = out + OFF_VEC + ((size_t)b * 2) * Him * Wim + y * Wim;

#pragma unroll
    for (int pt = 0; pt < 4; ++pt) {
#pragma unroll
        for (int q = 0; q < 4; ++q) {
            float s0 = 0.f, s1 = 0.f, s2 = 0.f, s3 = 0.f;
#pragma unroll
            for (int nt = 0; nt < 8; ++nt) {
                float h = fmaf(al[nt], acc[pt][nt][q], bt[nt]);
                h = fmaxf(h, 0.f);
                if (nt < 4) { s0 = fmaf(wa[nt], h, s0); s1 = fmaf(wb[nt], h, s1); }
                else        { s2 = fmaf(wa[nt], h, s2); s3 = fmaf(wb[nt], h, s3); }
            }
#pragma unroll
            for (int off = 1; off < 16; off <<= 1) {
                s0 += __shfl_xor(s0, off);
                s1 += __shfl_xor(s1, off);
                s2 += __shfl_xor(s2, off);
                s3 += __shfl_xor(s3, off);
            }
            int px = px0 + pt * 16 + ((lane >> 4) << 2) + q;
            if (l15 == 0) {
                outhm[px] = 1.f / (1.f + expf(-(s0 + bh0)));
            } else if (l15 == 1) {
                outhm[Him * Wim + px] = 1.f / (1.f + expf(-(s1 + bh1)));
            } else if (l15 == 2) {
                outvec[px] = s2 + bv0;
            } else if (l15 == 3) {
                outvec[Him * Wim + px] = s3 + bv1;
            }
        }
    }
}

// =====================================================================
// peak extraction: 1024 threads/block, 2 barriers/iteration
// =====================================================================
__global__ __launch_bounds__(1024) void peak_kernel(float* __restrict__ out)
{
    __shared__ float rowval[512];
    __shared__ int   rowcol[512];
    __shared__ int   sbx[NPK], sby[NPK];
    __shared__ int   s_grow;
    __shared__ int   ppx[NPK], ppy[NPK];

    int m = blockIdx.x;
    const float* hm = out + (size_t)m * (Him * Wim);
    int tid  = threadIdx.x;
    int lane = tid & 63;
    int wv   = tid >> 6;       // 0..15

    if (tid < NPK) { ppx[tid] = 0; ppy[tid] = 0; }

    // phase A: per-row (max, first argmax col); wave per row, 32 rows/wave
#pragma unroll 4
    for (int row = wv; row < 512; row += 16) {
        float4 v4 = *reinterpret_cast<const float4*>(hm + row * 256 + (lane << 2));
        float bv = v4.x; int bc = lane << 2;
        if (v4.y > bv) { bv = v4.y; bc = (lane << 2) + 1; }
        if (v4.z > bv) { bv = v4.z; bc = (lane << 2) + 2; }
        if (v4.w > bv) { bv = v4.w; bc = (lane << 2) + 3; }
#pragma unroll
        for (int off = 32; off; off >>= 1) {
            float ov = __shfl_xor(bv, off);
            int   oc = __shfl_xor(bc, off);
            if (ov > bv || (ov == bv && oc < bc)) { bv = ov; bc = oc; }
        }
        if (lane == 0) { rowval[row] = bv; rowcol[row] = bc; }
    }
    __syncthreads();

    for (int it = 0; it < NPK; ++it) {
        // wave0: global argmax over 512 rows (first-row tie-break)
        if (wv == 0) {
            float bv = rowval[lane]; int br = lane;
#pragma unroll
            for (int k = 1; k < 8; ++k) {
                float v = rowval[lane + 64 * k];
                if (v > bv) { bv = v; br = lane + 64 * k; }
            }
#pragma unroll
            for (int off = 32; off; off >>= 1) {
                float ov = __shfl_xor(bv, off);
                int   orr = __shfl_xor(br, off);
                if (ov > bv || (ov == bv && orr < br)) { bv = ov; br = orr; }
            }
            if (lane == 0) {
                if (bv > PTHRESH) {
                    int gc = rowcol[br];
                    ppx[it] = gc; ppy[it] = br;
                    sbx[it] = gc; sby[it] = br;
                    s_grow  = br;
                } else {
                    s_grow = -1;
                }
            }
        }
        __syncthreads();
        int grow = s_grow;
        if (grow < 0) break;   // uniform: all later peaks are (0,0), already zeroed

        // 11 waves rescan one row each with box exclusion
        if (wv < 11) {
            int row = grow - RAD + wv;
            if (row >= 0 && row < 512) {
                int nb = it + 1;
                float4 v4 = *reinterpret_cast<const float4*>(hm + row * 256 + (lane << 2));
                float vals[4] = { v4.x, v4.y, v4.z, v4.w };
                float bv2 = -1.f; int bc2 = 0;
#pragma unroll
                for (int q = 0; q < 4; ++q) {
                    int col = (lane << 2) + q;
                    float val = vals[q];
                    for (int i = 0; i < nb; ++i) {
                        int dy = row - sby[i]; if (dy < 0) dy = -dy;
                        int dx = col - sbx[i]; if (dx < 0) dx = -dx;
                        if (dy <= RAD && dx <= RAD) { val = 0.f; break; }
                    }
                    if (val > bv2) { bv2 = val; bc2 = col; }
                }
#pragma unroll
                for (int off = 32; off; off >>= 1) {
                    float ov = __shfl_xor(bv2, off);
                    int   oc = __shfl_xor(bc2, off);
                    if (ov > bv2 || (ov == bv2 && oc < bc2)) { bv2 = ov; bc2 = oc; }
                }
                if (lane == 0) { rowval[row] = bv2; rowcol[row] = bc2; }
            }
        }
        __syncthreads();
    }
    __syncthreads();

    // ordering: stable sort by y descending, invalid -> (0,0) at end
    if (tid == 0) {
        float key[NPK]; int ord[NPK];
        for (int i = 0; i < NPK; ++i) {
            int valid = (ppx[i] + ppy[i]) != 0;
            key[i] = valid ? (float)ppy[i] : -3.4e38f;
            ord[i] = i;
        }
        for (int i = 1; i < NPK; ++i) {
            int oi = ord[i]; float ki = key[oi];
            int j = i - 1;
            while (j >= 0 && key[ord[j]] < ki) { ord[j + 1] = ord[j]; --j; }
            ord[j + 1] = oi;
        }
        int bb = m >> 1, which = m & 1;
        float* dst = out + (which ? OFF_LO : OFF_UP) + bb * (NPK * 2);
        for (int i = 0; i < NPK; ++i) {
            int src = ord[i];
            int valid = (ppx[src] + ppy[src]) != 0;
            dst[i * 2 + 0] = valid ? (float)ppx[src] : 0.f;
            dst[i * 2 + 1] = valid ? (float)ppy[src] : 0.f;
        }
    }
}

__global__ __launch_bounds__(320) void mid_kernel(float* __restrict__ out)
{
    int t = threadIdx.x;
    if (t < Bn * NPK * 2)
        out[OFF_MID + t] = 0.5f * (out[OFF_UP + t] + out[OFF_LO + t]);
}

extern "C" void kernel_launch(void* const* d_in, const int* in_sizes, int n_in,
                              void* d_out, int out_size, void* d_ws, size_t ws_size,
                              hipStream_t stream)
{
    const float* x      = (const float*)d_in[0];
    const float* w1_hm  = (const float*)d_in[1];
    const float* b1_hm  = (const float*)d_in[2];
    const float* g_hm   = (const float*)d_in[3];
    const float* be_hm  = (const float*)d_in[4];
    const float* m_hm   = (const float*)d_in[5];
    const float* v_hm   = (const float*)d_in[6];
    const float* w2_hm  = (const float*)d_in[7];
    const float* b2_hm  = (const float*)d_in[8];
    const float* w1_vec = (const float*)d_in[9];
    const float* b1_vec = (const float*)d_in[10];
    const float* g_vec  = (const float*)d_in[11];
    const float* be_vec = (const float*)d_in[12];
    const float* m_vec  = (const float*)d_in[13];
    const float* v_vec  = (const float*)d_in[14];
    const float* w2_vec = (const float*)d_in[15];
    const float* b2_vec = (const float*)d_in[16];

    float* out = (float*)d_out;

    if (ws_size >= (size_t)WS_NEED) {
        f16*  xh   = (f16*)d_ws;
        char* wreg = (char*)d_ws + XH_BYTES;
        const float* btf = (const float*)(wreg + WBYTES);
        const float* waf = btf + 128;
        const float* wbf = btf + 256;

        xform_kernel<<<(Bn * PH * PW * 4 + 255) / 256, 256, 0, stream>>>(x, xh);
        prep4_kernel<<<144, 256, 0, stream>>>(
            w1_hm, b1_hm, g_hm, be_hm, m_hm, v_hm,
            w1_vec, b1_vec, g_vec, be_vec, m_vec, v_vec,
            w2_hm, w2_vec, wreg);
        conv7_kernel<<<1024, 512, 0, stream>>>(
            xh, (const f16*)wreg, btf, waf, wbf,
            b2_hm, b2_vec, out);
    } else {
        prep_fb_kernel<<<144, 256, 0, stream>>>(
            w1_hm, b1_hm, g_hm, be_hm, m_hm, v_hm,
            w1_vec, b1_vec, g_vec, be_vec, m_vec, v_vec, d_ws);
        conv_fb_kernel<<<Bn * Him, 256, 0, stream>>>(
            x, d_ws, w2_hm, b2_hm, w2_vec, b2_vec, out);
    }

    peak_kernel<<<Bn * 2, 1024, 0, stream>>>(out);

    mid_kernel<<<1, 320, 0, stream>>>(out);
}